// Round 9
// baseline (122.300 us; speedup 1.0000x reference)
//
#include <hip/hip_runtime.h>

// GCN aggregator: out[r,:] = relu( (1/25 * sum_s F[idx[r,s],:]) @ W )
// r in [0, 32768), D_IN = D_OUT = 128, S = 25.
//
// Round 12: Sc register prefetch — pure-line MSHR window in the gather.
//  r11 post-mortem: int8 G (one 128 B line/sample) + per-node scale landed
//  121.3 us, absmax unchanged. Decomposition: fills 84 (fixed) + gemm ~12.5
//  + gather ~25. Gather model: MSHR-bound; each sample issues a 128 B row
//  line (~600cy L3) AND a 4 B Sc load (L2-hot ~150cy) in the same window —
//  Sc occupies ~19% of outstanding-slot time. Fix: prefetch all 25 scales
//  into VGPRs BEFORE the line loop (vmcnt tracking lets batch 0 start once
//  its lines arrive); main loop issues only lines. Accuracy-neutral.

#define DEG 25
#define DIM 128

typedef __attribute__((ext_vector_type(8))) short short8;        // 8 bf16
typedef __attribute__((ext_vector_type(2))) float floatx2;       // 8 B
typedef __attribute__((ext_vector_type(4))) float floatx4;       // 16 B
typedef __attribute__((ext_vector_type(2))) unsigned int uintx2; // 8 B
typedef __attribute__((ext_vector_type(4))) unsigned int uintx4; // 16 B

__device__ __forceinline__ unsigned short f2bf(float f) {
    // round-to-nearest-even fp32 -> bf16 (inputs finite)
    unsigned u = __float_as_uint(f);
    return (unsigned short)((u + 0x7fffu + ((u >> 16) & 1u)) >> 16);
}

// ---------------------------------------------------------------- GEMM ------
// Gq[node][p] int8 (permuted: byte p = 8*l16 + nt <=> col 16*nt + l16),
// Sc[node] = rowmax/127. 128-row blocks, 4 waves, 32 rows/wave via MFMA.
#define BSTRIDE 136

__global__ __launch_bounds__(256, 2) void gemm_fw_q8(
    const float* __restrict__ A,       // [M,128] fp32
    const float* __restrict__ B,       // [128,128] fp32
    unsigned char* __restrict__ Gq,    // [M][128] int8, permuted cols
    float* __restrict__ Sc,            // [M] fp32 per-node scale
    int M)
{
    __shared__ unsigned short sBt[DIM * BSTRIDE];  // B^T [n][k], 34.8 KB

    const int tid = threadIdx.x;

    // ---- stage B transposed with fp32->bf16 (once per block)
    {
        const float4* B4 = (const float4*)B;
#pragma unroll
        for (int i = 0; i < 16; ++i) {
            const int linear = i * 256 + tid;   // 0..4095 float4s
            const int k  = linear >> 5;         // B row
            const int c4 = linear & 31;         // float4 within row
            const float4 v = B4[linear];
            const int n = c4 * 4;
            sBt[(n + 0) * BSTRIDE + k] = f2bf(v.x);
            sBt[(n + 1) * BSTRIDE + k] = f2bf(v.y);
            sBt[(n + 2) * BSTRIDE + k] = f2bf(v.z);
            sBt[(n + 3) * BSTRIDE + k] = f2bf(v.w);
        }
    }
    __syncthreads();

    const int wave = tid >> 6;
    const int lane = tid & 63;
    const int quad = lane >> 4;    // 0..3
    const int l16  = lane & 15;

    const int rw0 = blockIdx.x * 128 + wave * 32;   // wave's first row

    floatx4 acc[2][8];
#pragma unroll
    for (int mt = 0; mt < 2; ++mt)
#pragma unroll
        for (int nt = 0; nt < 8; ++nt)
            acc[mt][nt] = (floatx4){0.f, 0.f, 0.f, 0.f};

#pragma unroll
    for (int kt = 0; kt < 4; ++kt) {
        const int k0 = kt * 32;

        // A-frags: lane holds A[m=l16][k=k0+quad*8+j], j=0..7.
        short8 afrag[2];
#pragma unroll
        for (int mt = 0; mt < 2; ++mt) {
            int row = rw0 + mt * 16 + l16;
            if (row >= M) row = M - 1;          // tail clamp (stores guarded)
            const float* ap = A + (size_t)row * DIM + k0 + quad * 8;
            const float4 x = *(const float4*)ap;
            const float4 y = *(const float4*)(ap + 4);
            unsigned p0 = (unsigned)f2bf(x.x) | ((unsigned)f2bf(x.y) << 16);
            unsigned p1 = (unsigned)f2bf(x.z) | ((unsigned)f2bf(x.w) << 16);
            unsigned p2 = (unsigned)f2bf(y.x) | ((unsigned)f2bf(y.y) << 16);
            unsigned p3 = (unsigned)f2bf(y.z) | ((unsigned)f2bf(y.w) << 16);
            uintx4 packed = (uintx4){p0, p1, p2, p3};
            afrag[mt] = __builtin_bit_cast(short8, packed);
        }

        // B-frags from LDS: lane holds B[k=k0+quad*8+j][n=nt*16+l16]
#pragma unroll
        for (int nt = 0; nt < 8; ++nt) {
            const uintx4 u = *(const uintx4*)&sBt[(nt * 16 + l16) * BSTRIDE + k0 + quad * 8];
            const short8 bfrag = __builtin_bit_cast(short8, u);
#pragma unroll
            for (int mt = 0; mt < 2; ++mt)
                acc[mt][nt] = __builtin_amdgcn_mfma_f32_16x16x32_bf16(
                    afrag[mt], bfrag, acc[mt][nt], 0, 0, 0);
        }
    }

    // ---- epilogue: per-row max (shfl over the 16 l16-lanes holding the
    // row's 128 cols), quantize to int8, pack 8 B, direct global store.
    // C/D frag: elem r of lane = (row 16mt+quad*4+r, col 16nt+l16).
#pragma unroll
    for (int mt = 0; mt < 2; ++mt) {
#pragma unroll
        for (int r = 0; r < 4; ++r) {
            float m = fabsf(acc[mt][0][r]);
#pragma unroll
            for (int nt = 1; nt < 8; ++nt)
                m = fmaxf(m, fabsf(acc[mt][nt][r]));
            // reduce over the 16 lanes of this quad (l16 dimension)
            m = fmaxf(m, __shfl_xor(m, 1));
            m = fmaxf(m, __shfl_xor(m, 2));
            m = fmaxf(m, __shfl_xor(m, 4));
            m = fmaxf(m, __shfl_xor(m, 8));

            const int node = rw0 + mt * 16 + quad * 4 + r;
            const float is = (m > 0.f) ? 127.f / m : 0.f;
            if (l16 == 0 && node < M)
                Sc[node] = m * (1.f / 127.f);

            if (node < M) {
                unsigned lo = 0, hi = 0;
#pragma unroll
                for (int nt = 0; nt < 4; ++nt) {
                    float t = rintf(acc[mt][nt][r] * is);
                    t = fmaxf(-127.f, fminf(127.f, t));
                    lo |= ((unsigned)((int)t & 255)) << (8 * nt);
                }
#pragma unroll
                for (int nt = 4; nt < 8; ++nt) {
                    float t = rintf(acc[mt][nt][r] * is);
                    t = fmaxf(-127.f, fminf(127.f, t));
                    hi |= ((unsigned)((int)t & 255)) << (8 * (nt - 4));
                }
                // byte positions l16*8 .. l16*8+7 of the node's 128 B row;
                // the wave's 16 l16-lanes cover the full row => 4 complete
                // 128 B rows per store instruction.
                *(uintx2*)(Gq + (size_t)node * DIM + l16 * 8) = (uintx2){lo, hi};
            }
        }
    }
}

// ------------------------------------------------------- gather-mean-relu ---
// out[r, col(k)] = relu( 1/25 * sum_s Sc[n_s] * q[n_s][16*oct+k] ),
// col(k) = 16*(k&7) + 2*oct + (k>>3). One 128 B line per sample; all 25
// scales prefetched to VGPRs so the load loop issues pure line traffic.
#define GRB 32

__global__ __launch_bounds__(256, 4) void gather_q8(
    const unsigned char* __restrict__ Gq,   // [n_nodes][128] int8 permuted
    const float* __restrict__ Sc,           // [n_nodes] scales
    const int* __restrict__ idx,            // [n_rows,25]
    float* __restrict__ out,                // [n_rows,128] fp32
    int n_rows)
{
    __shared__ int sIdx[GRB * DEG];         // 3.2 KB

    const int tid  = threadIdx.x;
    const int row0 = blockIdx.x * GRB;

    const int* ib = idx + (size_t)row0 * DEG;
    for (int i = tid; i < GRB * DEG; i += 256)
        sIdx[i] = __builtin_nontemporal_load(ib + i);
    __syncthreads();

    const int oct = tid & 7;                // 16 B sub-chunk of 128 B row
    const int r   = tid >> 3;               // 0..31: this thread's row
    const uintx4* __restrict__ G4 = (const uintx4*)Gq + oct;
    const int* lp = &sIdx[r * DEG];

    // ---- prefetch all 25 scales first (L2-hot, resolve early); the main
    // loop then issues ONLY 128 B row lines into the MSHR window.
    float sc[DEG];
#pragma unroll
    for (int s = 0; s < DEG; ++s)
        sc[s] = Sc[lp[s]];

    float acc[16];
#pragma unroll
    for (int k = 0; k < 16; ++k) acc[k] = 0.f;

#define ACC16(v, s)                                             \
    do {                                                        \
        _Pragma("unroll")                                       \
        for (int d = 0; d < 4; ++d) {                           \
            const unsigned u = (v)[d];                          \
            acc[4*d + 0] += (s) * (float)((int)(u << 24) >> 24);\
            acc[4*d + 1] += (s) * (float)((int)(u << 16) >> 24);\
            acc[4*d + 2] += (s) * (float)((int)(u <<  8) >> 24);\
            acc[4*d + 3] += (s) * (float)((int)u >> 24);        \
        }                                                       \
    } while (0)

#pragma unroll
    for (int sb = 0; sb < 5; ++sb) {        // 5 batches of 5 line loads
        const uintx4 v0 = G4[(size_t)lp[sb*5+0] * 8];
        const uintx4 v1 = G4[(size_t)lp[sb*5+1] * 8];
        const uintx4 v2 = G4[(size_t)lp[sb*5+2] * 8];
        const uintx4 v3 = G4[(size_t)lp[sb*5+3] * 8];
        const uintx4 v4 = G4[(size_t)lp[sb*5+4] * 8];
        ACC16(v0, sc[sb*5+0]); ACC16(v1, sc[sb*5+1]); ACC16(v2, sc[sb*5+2]);
        ACC16(v3, sc[sb*5+3]); ACC16(v4, sc[sb*5+4]);
    }
#undef ACC16

    const float inv = 1.0f / 25.0f;
    // acc[k] is col 16*(k&7) + 2*oct + (k>>3): per j the pair (k=j, k=j+8)
    // is 2 consecutive floats; 8 octs cover 16 consecutive cols per j.
    float* orow = out + (size_t)(row0 + r) * DIM + oct * 2;
#pragma unroll
    for (int j = 0; j < 8; ++j) {
        const floatx2 w = {fmaxf(acc[j] * inv, 0.f),
                           fmaxf(acc[j + 8] * inv, 0.f)};
        __builtin_nontemporal_store(w, (floatx2*)(orow + 16 * j));
    }
}

// --------------------------------------------- fallback (round-2 kernel) ----
#define RPB 16
#define CG 32

__device__ __forceinline__ float4 relu4(float4 v) {
    return make_float4(fmaxf(v.x, 0.f), fmaxf(v.y, 0.f),
                       fmaxf(v.z, 0.f), fmaxf(v.w, 0.f));
}

__global__ __launch_bounds__(256, 4) void gcn_fused(
    const float* __restrict__ F, const int* __restrict__ idx,
    const float* __restrict__ W, float* __restrict__ out, int n_rows)
{
    __shared__ float4 sV[RPB * CG];
    __shared__ int    sIdx[RPB * DEG];

    const float4* F4 = (const float4*)F;
    const float4* W4 = (const float4*)W;
    float4* out4 = (float4*)out;

    const int tid = threadIdx.x;
    const int row0 = blockIdx.x * RPB;

    for (int i = tid; i < RPB * DEG; i += 256)
        sIdx[i] = idx[(size_t)row0 * DEG + i];
    __syncthreads();

    const int cg32 = tid & 31;
    const int rs = tid >> 5;

#pragma unroll
    for (int rr = 0; rr < 2; ++rr) {
        const int r = rs + rr * 8;
        int j[DEG];
#pragma unroll
        for (int s = 0; s < DEG; ++s) j[s] = sIdx[r * DEG + s];
        float4 acc = make_float4(0.f, 0.f, 0.f, 0.f);
#pragma unroll
        for (int s = 0; s < DEG; ++s) {
            float4 f = F4[(size_t)j[s] * CG + cg32];
            acc.x += f.x; acc.y += f.y; acc.z += f.z; acc.w += f.w;
        }
        const float inv = 1.0f / 25.0f;
        acc.x *= inv; acc.y *= inv; acc.z *= inv; acc.w *= inv;
        sV[r * CG + cg32] = acc;
    }
    __syncthreads();

    const float4* vA = &sV[rs * CG];
    const float4* vB = &sV[(rs + 8) * CG];
    float4 o0 = make_float4(0.f, 0.f, 0.f, 0.f);
    float4 o1 = make_float4(0.f, 0.f, 0.f, 0.f);
#pragma unroll 4
    for (int d4 = 0; d4 < CG; ++d4) {
        const float4 a = vA[d4];
        const float4 b = vB[d4];
        const float4 w0 = W4[(size_t)(4 * d4 + 0) * CG + cg32];
        const float4 w1 = W4[(size_t)(4 * d4 + 1) * CG + cg32];
        const float4 w2 = W4[(size_t)(4 * d4 + 2) * CG + cg32];
        const float4 w3 = W4[(size_t)(4 * d4 + 3) * CG + cg32];
        o0.x += a.x*w0.x + a.y*w1.x + a.z*w2.x + a.w*w3.x;
        o0.y += a.x*w0.y + a.y*w1.y + a.z*w2.y + a.w*w3.y;
        o0.z += a.x*w0.z + a.y*w1.z + a.z*w2.z + a.w*w3.z;
        o0.w += a.x*w0.w + a.y*w1.w + a.z*w2.w + a.w*w3.w;
        o1.x += b.x*w0.x + b.y*w1.x + b.z*w2.x + b.w*w3.x;
        o1.y += b.x*w0.y + b.y*w1.y + b.z*w2.y + b.w*w3.y;
        o1.z += b.x*w0.z + b.y*w1.z + b.z*w2.z + b.w*w3.z;
        o1.w += b.x*w0.w + b.y*w1.w + b.z*w2.w + b.w*w3.w;
    }
    out4[(size_t)(row0 + rs) * CG + cg32]     = relu4(o0);
    out4[(size_t)(row0 + rs + 8) * CG + cg32] = relu4(o1);
}

// ----------------------------------------------------------------------------
extern "C" void kernel_launch(void* const* d_in, const int* in_sizes, int n_in,
                              void* d_out, int out_size, void* d_ws, size_t ws_size,
                              hipStream_t stream) {
    const float* F   = (const float*)d_in[0];   // features [100000,128] fp32
    const int*   idx = (const int*)d_in[1];     // sample_res [8,4096,25] int32
    const float* W   = (const float*)d_in[2];   // weights [128,128] fp32
    float* out = (float*)d_out;                 // [8,4096,128] fp32

    const int n_nodes = in_sizes[0] / DIM;      // 100000
    const int n_rows  = in_sizes[1] / DEG;      // 32768

    const size_t gq_bytes = (size_t)n_nodes * DIM;              // int8 table
    const size_t sc_off   = (gq_bytes + 127) & ~(size_t)127;
    const size_t need     = sc_off + (size_t)n_nodes * sizeof(float);

    if (ws_size >= need && (n_rows & (GRB - 1)) == 0) {
        unsigned char* Gq = (unsigned char*)d_ws;
        float* Sc = (float*)((char*)d_ws + sc_off);
        gemm_fw_q8<<<(n_nodes + 127) / 128, 256, 0, stream>>>(F, W, Gq, Sc, n_nodes);
        gather_q8<<<n_rows / GRB, 256, 0, stream>>>(Gq, Sc, idx, out, n_rows);
    } else {
        gcn_fused<<<n_rows / RPB, 256, 0, stream>>>(F, idx, W, out, n_rows);
    }
}